// Round 2
// baseline (1968.627 us; speedup 1.0000x reference)
//
#include <hip/hip_runtime.h>
#include <hip/hip_bf16.h>

#define BB 4
#define LL 128
#define DM 256
#define VV 50257
#define DW 768
#define HH 8
#define EE 32

typedef __hip_bfloat16 bf16;

// ---------------- Q projection: [512,256] = tse @ Wq + bq (fp32 out) --------
__global__ __launch_bounds__(256) void qproj_kernel(
    const float* __restrict__ tse, const float* __restrict__ Wq,
    const float* __restrict__ bq, float* __restrict__ Qf) {
  __shared__ float row[DM];
  int r = blockIdx.x;     // 0..511
  int n = threadIdx.x;    // 0..255
  row[n] = tse[r * DM + n];
  __syncthreads();
  float acc = bq[n];
#pragma unroll 8
  for (int k = 0; k < DM; ++k)
    acc = fmaf(row[k], Wq[k * DM + n], acc);
  Qf[r * DM + n] = acc;
}

// ------------- K,V projection: [V,768]@[768,256] x2, bf16 out ---------------
// Block handles 8 vocab rows; thread n owns column n for all 8 rows.
__global__ __launch_bounds__(256) void kvproj_kernel(
    const float* __restrict__ WE, const float* __restrict__ Wk,
    const float* __restrict__ bk, const float* __restrict__ Wv,
    const float* __restrict__ bv, bf16* __restrict__ Kb, bf16* __restrict__ Vb) {
  const int RV = 8;
  __shared__ float we[RV][DW];  // 24 KB
  int v0 = blockIdx.x * RV;
  int t = threadIdx.x;
  for (int i = t; i < RV * DW; i += 256) {
    int rr = i / DW, kk = i - rr * DW;
    int v = v0 + rr;
    we[rr][kk] = (v < VV) ? WE[(size_t)v * DW + kk] : 0.f;
  }
  __syncthreads();
  int n = t;
  float ak[RV], av[RV];
  float bkv = bk[n];
  float bvv = bv[n];
#pragma unroll
  for (int r = 0; r < RV; ++r) { ak[r] = bkv; av[r] = bvv; }
#pragma unroll 4
  for (int k = 0; k < DW; ++k) {
    float wk = Wk[k * DM + n];
    float wv = Wv[k * DM + n];
#pragma unroll
    for (int r = 0; r < RV; ++r) {
      ak[r] = fmaf(we[r][k], wk, ak[r]);
      av[r] = fmaf(we[r][k], wv, av[r]);
    }
  }
#pragma unroll
  for (int r = 0; r < RV; ++r) {
    int v = v0 + r;
    if (v < VV) {
      Kb[(size_t)v * DM + n] = __float2bfloat16(ak[r]);
      Vb[(size_t)v * DM + n] = __float2bfloat16(av[r]);
    }
  }
}

// ---------------- zero the reprog accumulator -------------------------------
__global__ void zero_kernel(float* __restrict__ p, int n) {
  int i = blockIdx.x * blockDim.x + threadIdx.x;
  if (i < n) p[i] = 0.f;
}

// ---------------- fused attention over the vocab axis -----------------------
// grid = 32 (b,h) * bpb chunks. Each block streams 64-row V-tiles:
//   phase1: s[v][l] = scale * <Q[l,:], K[v,:]>   (Q cached in 32 regs/thread)
//   softmax over l per v-row (rows independent!)
//   phase2: acc[l][e] += attn[v][l] * V[v][e]    (regs), atomicAdd at end.
__global__ __launch_bounds__(256) void attn_kernel(
    const float* __restrict__ Qf, const bf16* __restrict__ Kb,
    const bf16* __restrict__ Vb, float* __restrict__ reprog, int bpb) {
  __shared__ union {
    float Qs[LL][EE + 1];   // 16.9 KB, used only before tile loop
    float st[64][LL + 1];   // 33 KB (padded: stride 129 -> 2-way banks)
  } u;
  __shared__ float ks[64][EE + 1];  // 8.25 KB
  __shared__ float vt[64][EE + 1];  // 8.25 KB
  __shared__ float red[64][4];

  int bh = blockIdx.x / bpb;
  int chunk = blockIdx.x - bh * bpb;
  int b = bh >> 3, h = bh & 7;
  int t = threadIdx.x;

  for (int i = t; i < LL * EE; i += 256) {
    int l = i >> 5, e = i & 31;
    u.Qs[l][e] = Qf[(size_t)(b * LL + l) * DM + h * EE + e];
  }
  __syncthreads();

  // phase-1 identity: thread owns query row l_q, half vh of the 64 v-rows
  const int l_q = t & 127;
  const int vh = t >> 7;  // wave-uniform
  float qreg[EE];
#pragma unroll
  for (int e = 0; e < EE; ++e) qreg[e] = u.Qs[l_q][e];

  // phase-2 identity: thread owns (e_own, 16 l-rows starting at lb)
  const int e_own = t & 31;
  const int lb = (t >> 5) * 16;
  float acc[16];
#pragma unroll
  for (int j = 0; j < 16; ++j) acc[j] = 0.f;

  const float scale = 0.17677669529663687f;  // 1/sqrt(32)
  const int ntiles = (VV + 63) >> 6;         // 786

  for (int tile = chunk; tile < ntiles; tile += bpb) {
    int v0 = tile << 6;
    __syncthreads();  // prev phase2 done; also fences Qs->st union reuse
    for (int i = t; i < 64 * EE; i += 256) {
      int vr = i >> 5, e = i & 31;
      int v = v0 + vr;
      if (v < VV) {
        ks[vr][e] = __bfloat162float(Kb[(size_t)v * DM + h * EE + e]);
        vt[vr][e] = __bfloat162float(Vb[(size_t)v * DM + h * EE + e]);
      } else {  // tail rows: V=0 kills their (garbage-softmax) contribution
        ks[vr][e] = 0.f;
        vt[vr][e] = 0.f;
      }
    }
    __syncthreads();
    // phase 1: ks reads are wave-broadcast (vr uniform per instr), Q in regs
#pragma unroll 2
    for (int vi = 0; vi < 32; ++vi) {
      int vr = vh * 32 + vi;
      float s = 0.f;
#pragma unroll
      for (int e = 0; e < EE; ++e) s = fmaf(qreg[e], ks[vr][e], s);
      u.st[vr][l_q] = s * scale;
    }
    __syncthreads();
    // softmax over l (length 128) per v-row; 4 threads per row
    {
      int r = t >> 2, q = t & 3;
      int l0 = q * 32;
      float m = -1e30f;
      for (int l = l0; l < l0 + 32; ++l) m = fmaxf(m, u.st[r][l]);
      red[r][q] = m;
      __syncthreads();
      m = fmaxf(fmaxf(red[r][0], red[r][1]), fmaxf(red[r][2], red[r][3]));
      __syncthreads();
      float ssum = 0.f;
      for (int l = l0; l < l0 + 32; ++l) {
        float ex = __expf(u.st[r][l] - m);
        u.st[r][l] = ex;
        ssum += ex;
      }
      red[r][q] = ssum;
      __syncthreads();
      float inv = 1.f / (red[r][0] + red[r][1] + red[r][2] + red[r][3]);
      for (int l = l0; l < l0 + 32; ++l) u.st[r][l] *= inv;
    }
    __syncthreads();
    // phase 2: vt read once per vr (broadcast-ish), st 2 addrs/wave
    for (int vr = 0; vr < 64; ++vr) {
      float w = vt[vr][e_own];
#pragma unroll
      for (int j = 0; j < 16; ++j)
        acc[j] = fmaf(u.st[vr][lb + j], w, acc[j]);
    }
  }
#pragma unroll
  for (int j = 0; j < 16; ++j)
    atomicAdd(&reprog[(size_t)(b * LL + lb + j) * DM + h * EE + e_own], acc[j]);
}

// ---------------- output projection: reprog @ Wo + bo -> fp32 out -----------
__global__ __launch_bounds__(256) void outproj_kernel(
    const float* __restrict__ reprog, const float* __restrict__ Wo,
    const float* __restrict__ bo, float* __restrict__ out) {
  __shared__ float row[DM];
  int r = blockIdx.x, n = threadIdx.x;
  row[n] = reprog[r * DM + n];
  __syncthreads();
  float acc = bo[n];
#pragma unroll 8
  for (int k = 0; k < DM; ++k)
    acc = fmaf(row[k], Wo[k * DM + n], acc);
  out[r * DM + n] = acc;
}

extern "C" void kernel_launch(void* const* d_in, const int* in_sizes, int n_in,
                              void* d_out, int out_size, void* d_ws, size_t ws_size,
                              hipStream_t stream) {
  const float* tse = (const float*)d_in[0];
  const float* WE  = (const float*)d_in[1];
  const float* Wq  = (const float*)d_in[2];
  const float* bq  = (const float*)d_in[3];
  const float* Wk  = (const float*)d_in[4];
  const float* bk  = (const float*)d_in[5];
  const float* Wv  = (const float*)d_in[6];
  const float* bv  = (const float*)d_in[7];
  const float* Wo  = (const float*)d_in[8];
  const float* bo  = (const float*)d_in[9];
  float* out = (float*)d_out;

  // ws layout: Qf fp32 | Kb bf16 | Vb bf16 | reprog fp32  (~54.2 MB total)
  char* ws = (char*)d_ws;
  const size_t QF_BYTES = (size_t)BB * LL * DM * 4;       // 524288
  const size_t KV_BYTES = (size_t)VV * DM * 2;            // 25731584
  float* Qf     = (float*)ws;
  bf16*  Kb     = (bf16*)(ws + QF_BYTES);
  bf16*  Vb     = (bf16*)(ws + QF_BYTES + KV_BYTES);
  float* reprog = (float*)(ws + QF_BYTES + 2 * KV_BYTES);

  const int BPB = 24;  // v-chunks per (b,h): grid = 32*24 = 768 blocks

  qproj_kernel<<<BB * LL, 256, 0, stream>>>(tse, Wq, bq, Qf);
  kvproj_kernel<<<(VV + 7) / 8, 256, 0, stream>>>(WE, Wk, bk, Wv, bv, Kb, Vb);
  zero_kernel<<<(BB * LL * DM + 255) / 256, 256, 0, stream>>>(reprog, BB * LL * DM);
  attn_kernel<<<32 * BPB, 256, 0, stream>>>(Qf, Kb, Vb, reprog, BPB);
  outproj_kernel<<<BB * LL, 256, 0, stream>>>(reprog, Wo, bo, out);
}

// Round 3
// 1012.158 us; speedup vs baseline: 1.9450x; 1.9450x over previous
//
#include <hip/hip_runtime.h>
#include <hip/hip_bf16.h>
#include <string.h>

#define BB 4
#define LL 128
#define DM 256
#define VV 50257
#define VPAD 50304   // 786 tiles * 64
#define DW 768
#define HH 8
#define EE 32

typedef __attribute__((ext_vector_type(8))) short sh8;    // 8 bf16 = 4 VGPR
typedef __attribute__((ext_vector_type(4))) float f32x4;  // MFMA accum

static __device__ inline unsigned short bfbits(float x) {
  __hip_bfloat16 h = __float2bfloat16(x);
  unsigned short u;
  __builtin_memcpy(&u, &h, 2);
  return u;
}

// ---------------- Q projection: Qb = bf16(scale * (tse @ Wq + bq)) ----------
__global__ __launch_bounds__(256) void qproj_kernel(
    const float* __restrict__ tse, const float* __restrict__ Wq,
    const float* __restrict__ bq, unsigned short* __restrict__ Qb) {
  __shared__ float row[DM];
  int r = blockIdx.x;     // 0..511
  int n = threadIdx.x;    // 0..255
  row[n] = tse[r * DM + n];
  __syncthreads();
  float acc = bq[n];
#pragma unroll 8
  for (int k = 0; k < DM; ++k)
    acc = fmaf(row[k], Wq[k * DM + n], acc);
  const float scale = 0.17677669529663687f;  // 1/sqrt(32), folded into Q
  Qb[r * DM + n] = bfbits(acc * scale);
}

// ------------- K,V projection: [V,768]@[768,256] x2, bf16 out ---------------
// Rows [VV, VPAD) written as zeros so attn tail tiles are well-defined.
__global__ __launch_bounds__(256) void kvproj_kernel(
    const float* __restrict__ WE, const float* __restrict__ Wk,
    const float* __restrict__ bk, const float* __restrict__ Wv,
    const float* __restrict__ bv, unsigned short* __restrict__ Kb,
    unsigned short* __restrict__ Vb) {
  const int RV = 8;
  __shared__ float we[RV][DW];  // 24 KB
  int v0 = blockIdx.x * RV;
  int t = threadIdx.x;
  for (int i = t; i < RV * DW; i += 256) {
    int rr = i / DW, kk = i - rr * DW;
    int v = v0 + rr;
    we[rr][kk] = (v < VV) ? WE[(size_t)v * DW + kk] : 0.f;
  }
  __syncthreads();
  int n = t;
  float ak[RV], av[RV];
  float bkv = bk[n];
  float bvv = bv[n];
#pragma unroll
  for (int r = 0; r < RV; ++r) { ak[r] = bkv; av[r] = bvv; }
#pragma unroll 4
  for (int k = 0; k < DW; ++k) {
    float wk = Wk[k * DM + n];
    float wv = Wv[k * DM + n];
#pragma unroll
    for (int r = 0; r < RV; ++r) {
      ak[r] = fmaf(we[r][k], wk, ak[r]);
      av[r] = fmaf(we[r][k], wv, av[r]);
    }
  }
#pragma unroll
  for (int r = 0; r < RV; ++r) {
    int v = v0 + r;
    if (v < VV) {
      Kb[(size_t)v * DM + n] = bfbits(ak[r]);
      Vb[(size_t)v * DM + n] = bfbits(av[r]);
    } else {  // v < VPAD always (grid covers exactly VPAD rows)
      Kb[(size_t)v * DM + n] = 0;
      Vb[(size_t)v * DM + n] = 0;
    }
  }
}

// ---------------- zero the reprog accumulator -------------------------------
__global__ void zero_kernel(float* __restrict__ p, int n) {
  int i = blockIdx.x * blockDim.x + threadIdx.x;
  if (i < n) p[i] = 0.f;
}

// ---------------- MFMA attention over the vocab axis ------------------------
// Per block: stream 64-v-row tiles for one (b,h).
//  phase1: S[64x128] = K_tile · Q^T via 16x16x32 bf16 MFMA (wave w: v rows
//          16w..16w+16). A-frag (K) + B-frags (Q, hoisted) load straight from
//          global — no LDS. Softmax over l done in registers via __shfl_xor
//          within 16-lane quad groups. P written bf16 to Pb[l][v] (= PV
//          A-operand layout).
//  phase2: out[l][e] += P^T · V_tile via MFMA; V staged transposed Vt[e][v].
#define PST 72  // row stride (bf16) for Pb/Vt: 144 B = 16 B aligned
__global__ __launch_bounds__(256) void attn_kernel(
    const unsigned short* __restrict__ Qb, const unsigned short* __restrict__ Kb,
    const unsigned short* __restrict__ Vb, float* __restrict__ reprog, int bpb) {
  __shared__ short Pb[LL * PST];  // 18432 B
  __shared__ short Vt[EE * PST];  //  4608 B

  int bh = blockIdx.x / bpb;
  int chunk = blockIdx.x - bh * bpb;
  int b = bh >> 3, h = bh & 7;
  int t = threadIdx.x;
  int w = t >> 6;         // wave 0..3
  int lane = t & 63;
  int a = lane & 15;      // MFMA n / m lane coord
  int quad = lane >> 4;   // 0..3

  // hoist Q B-frags: frag[tau] holds Q rows l=tau*16+a, e=quad*8+j (16B each)
  sh8 qf[8];
  const unsigned short* qbase = Qb + (size_t)(b * LL) * DM + h * EE;
#pragma unroll
  for (int tau = 0; tau < 8; ++tau)
    qf[tau] = *(const sh8*)(qbase + (size_t)(tau * 16 + a) * DM + quad * 8);

  f32x4 C[2][2];  // accum: l = 32w + mb*16 + quad*4 + r, e = nb*16 + a
#pragma unroll
  for (int mb = 0; mb < 2; ++mb)
#pragma unroll
    for (int nb = 0; nb < 2; ++nb)
      C[mb][nb] = (f32x4){0.f, 0.f, 0.f, 0.f};

  const int ntiles = VPAD >> 6;  // 786
  for (int tile = chunk; tile < ntiles; tile += bpb) {
    int v0 = tile << 6;
    __syncthreads();  // prev phase2 done reading Pb/Vt

    // phase-1 A-frag: K row v = v0 + 16w + a, k=e = quad*8+j  (issue first)
    sh8 af = *(const sh8*)(Kb + (size_t)(v0 + 16 * w + a) * DM + h * EE + quad * 8);
    // V tile load for transposed staging (in flight during MFMA+softmax)
    int vr = t >> 2, e0 = (t & 3) * 8;
    sh8 vv = *(const sh8*)(Vb + (size_t)(v0 + vr) * DM + h * EE + e0);

    // scores: 8 MFMAs -> lane holds S for v rows {16w+quad*4+r}, l = tau*16+a
    f32x4 S[8];
#pragma unroll
    for (int tau = 0; tau < 8; ++tau) {
      f32x4 z = {0.f, 0.f, 0.f, 0.f};
      S[tau] = __builtin_amdgcn_mfma_f32_16x16x32_bf16(af, qf[tau], z, 0, 0, 0);
    }

    // register softmax over l (8 taus x 16 lanes of quad-group) per v-row r
    float mx[4], sm[4], inv[4];
#pragma unroll
    for (int r = 0; r < 4; ++r) {
      float m = S[0][r];
#pragma unroll
      for (int tau = 1; tau < 8; ++tau) m = fmaxf(m, S[tau][r]);
      mx[r] = m;
    }
#pragma unroll
    for (int msk = 1; msk <= 8; msk <<= 1)
#pragma unroll
      for (int r = 0; r < 4; ++r)
        mx[r] = fmaxf(mx[r], __shfl_xor(mx[r], msk));
#pragma unroll
    for (int r = 0; r < 4; ++r) sm[r] = 0.f;
#pragma unroll
    for (int tau = 0; tau < 8; ++tau)
#pragma unroll
      for (int r = 0; r < 4; ++r) {
        float ex = __expf(S[tau][r] - mx[r]);
        S[tau][r] = ex;
        sm[r] += ex;
      }
#pragma unroll
    for (int msk = 1; msk <= 8; msk <<= 1)
#pragma unroll
      for (int r = 0; r < 4; ++r)
        sm[r] += __shfl_xor(sm[r], msk);
#pragma unroll
    for (int r = 0; r < 4; ++r) inv[r] = 1.f / sm[r];

    // stage V^T: Vt[e][v_local]  (8 b16 scatter writes per thread)
    {
      const short* vs = (const short*)&vv;
#pragma unroll
      for (int j = 0; j < 8; ++j)
        Vt[(e0 + j) * PST + vr] = vs[j];
    }
    // write P^T bf16: Pb[l = tau*16+a][v_local = 16w + quad*4 + r]
#pragma unroll
    for (int tau = 0; tau < 8; ++tau) {
      ushort4 pk;
      pk.x = bfbits(S[tau][0] * inv[0]);
      pk.y = bfbits(S[tau][1] * inv[1]);
      pk.z = bfbits(S[tau][2] * inv[2]);
      pk.w = bfbits(S[tau][3] * inv[3]);
      *(ushort4*)&Pb[(tau * 16 + a) * PST + 16 * w + quad * 4] = pk;
    }
    __syncthreads();

    // phase 2: C[l][e] += P^T[l][v] · V[v][e]
    sh8 Afr[2][2], Bfr[2][2];
#pragma unroll
    for (int mb = 0; mb < 2; ++mb)
#pragma unroll
      for (int kb = 0; kb < 2; ++kb)
        Afr[mb][kb] =
            *(const sh8*)&Pb[(32 * w + mb * 16 + a) * PST + kb * 32 + quad * 8];
#pragma unroll
    for (int kb = 0; kb < 2; ++kb)
#pragma unroll
      for (int nb = 0; nb < 2; ++nb)
        Bfr[kb][nb] = *(const sh8*)&Vt[(nb * 16 + a) * PST + kb * 32 + quad * 8];
#pragma unroll
    for (int kb = 0; kb < 2; ++kb)
#pragma unroll
      for (int mb = 0; mb < 2; ++mb)
#pragma unroll
        for (int nb = 0; nb < 2; ++nb)
          C[mb][nb] = __builtin_amdgcn_mfma_f32_16x16x32_bf16(
              Afr[mb][kb], Bfr[kb][nb], C[mb][nb], 0, 0, 0);
  }

  // epilogue: one atomicAdd burst per block
#pragma unroll
  for (int mb = 0; mb < 2; ++mb)
#pragma unroll
    for (int nb = 0; nb < 2; ++nb)
#pragma unroll
      for (int r = 0; r < 4; ++r) {
        int l = 32 * w + mb * 16 + quad * 4 + r;
        int e = nb * 16 + a;
        atomicAdd(&reprog[(size_t)(b * LL + l) * DM + h * EE + e], C[mb][nb][r]);
      }
}

// ---------------- output projection: reprog @ Wo + bo -> fp32 out -----------
__global__ __launch_bounds__(256) void outproj_kernel(
    const float* __restrict__ reprog, const float* __restrict__ Wo,
    const float* __restrict__ bo, float* __restrict__ out) {
  __shared__ float row[DM];
  int r = blockIdx.x, n = threadIdx.x;
  row[n] = reprog[r * DM + n];
  __syncthreads();
  float acc = bo[n];
#pragma unroll 8
  for (int k = 0; k < DM; ++k)
    acc = fmaf(row[k], Wo[k * DM + n], acc);
  out[r * DM + n] = acc;
}

extern "C" void kernel_launch(void* const* d_in, const int* in_sizes, int n_in,
                              void* d_out, int out_size, void* d_ws, size_t ws_size,
                              hipStream_t stream) {
  const float* tse = (const float*)d_in[0];
  const float* WE  = (const float*)d_in[1];
  const float* Wq  = (const float*)d_in[2];
  const float* bq  = (const float*)d_in[3];
  const float* Wk  = (const float*)d_in[4];
  const float* bk  = (const float*)d_in[5];
  const float* Wv  = (const float*)d_in[6];
  const float* bv  = (const float*)d_in[7];
  const float* Wo  = (const float*)d_in[8];
  const float* bo  = (const float*)d_in[9];
  float* out = (float*)d_out;

  // ws layout: Qb bf16 | Kb bf16 (VPAD rows) | Vb bf16 (VPAD) | reprog fp32
  char* ws = (char*)d_ws;
  const size_t QB_BYTES = (size_t)BB * LL * DM * 2;    // 262144
  const size_t KV_BYTES = (size_t)VPAD * DM * 2;       // 25755648
  unsigned short* Qb = (unsigned short*)ws;
  unsigned short* Kb = (unsigned short*)(ws + QB_BYTES);
  unsigned short* Vb = (unsigned short*)(ws + QB_BYTES + KV_BYTES);
  float* reprog = (float*)(ws + QB_BYTES + 2 * KV_BYTES);

  const int BPB = 32;  // v-chunks per (b,h): grid = 32*32 = 1024 blocks

  qproj_kernel<<<BB * LL, 256, 0, stream>>>(tse, Wq, bq, Qb);
  kvproj_kernel<<<VPAD / 8, 256, 0, stream>>>(WE, Wk, bk, Wv, bv, Kb, Vb);
  zero_kernel<<<(BB * LL * DM + 255) / 256, 256, 0, stream>>>(reprog, BB * LL * DM);
  attn_kernel<<<32 * BPB, 256, 0, stream>>>(Qb, Kb, Vb, reprog, BPB);
  outproj_kernel<<<BB * LL, 256, 0, stream>>>(reprog, Wo, bo, out);
}

// Round 4
// 440.300 us; speedup vs baseline: 4.4711x; 2.2988x over previous
//
#include <hip/hip_runtime.h>
#include <hip/hip_bf16.h>
#include <string.h>

#define BB 4
#define LL 128
#define DM 256
#define VV 50257
#define VPAD 50304   // 786 tiles * 64; also 393 * 128
#define DW 768
#define HH 8
#define EE 32

typedef __attribute__((ext_vector_type(8))) short sh8;    // 8 bf16 = 4 VGPR
typedef __attribute__((ext_vector_type(4))) float f32x4;  // MFMA accum

static __device__ inline unsigned short bfbits(float x) {
  __hip_bfloat16 h = __float2bfloat16(x);
  unsigned short u;
  __builtin_memcpy(&u, &h, 2);
  return u;
}

// ---------------- Q projection: Qb = bf16(scale * (tse @ Wq + bq)) ----------
__global__ __launch_bounds__(256) void qproj_kernel(
    const float* __restrict__ tse, const float* __restrict__ Wq,
    const float* __restrict__ bq, unsigned short* __restrict__ Qb) {
  __shared__ float row[DM];
  int r = blockIdx.x;     // 0..511
  int n = threadIdx.x;    // 0..255
  row[n] = tse[r * DM + n];
  __syncthreads();
  float acc = bq[n];
#pragma unroll 8
  for (int k = 0; k < DM; ++k)
    acc = fmaf(row[k], Wq[k * DM + n], acc);
  const float scale = 0.17677669529663687f;  // 1/sqrt(32), folded into Q
  Qb[r * DM + n] = bfbits(acc * scale);
}

// ------- transpose+cast Wk/Wv fp32 [768][256] -> bf16 [256][768] ------------
// block = one output row n of one matrix; writes coalesced, reads L2-absorbed.
__global__ __launch_bounds__(256) void wtrans_kernel(
    const float* __restrict__ Wk, const float* __restrict__ Wv,
    unsigned short* __restrict__ Wkt, unsigned short* __restrict__ Wvt) {
  int bx = blockIdx.x;
  const float* src = (bx & 1) ? Wv : Wk;
  unsigned short* dst = (bx & 1) ? Wvt : Wkt;
  int n = bx >> 1;
  int t = threadIdx.x;
#pragma unroll
  for (int j = 0; j < 3; ++j) {
    int k = t + 256 * j;
    dst[(size_t)n * DW + k] = bfbits(src[(size_t)k * DM + n]);
  }
}

// ------------- K,V projection via MFMA: [VPAD,768]@[768,256] x2 -------------
// Block: 128 rows x 128 cols, both K and V (sharing the WE A-tiles).
// Waves 2x2: wave (wm,wn) = 4 mb x 4 nb x 2 mat = 32 MFMAs/k-tile,
// A reused 8x, B reused 4x. Rows [VV,VPAD) stored as 0 (attn needs zero pads).
#define KST 40  // LDS row stride in bf16 (80 B, 16B-aligned)
__global__ __launch_bounds__(256, 2) void kvproj_kernel(
    const float* __restrict__ WE, const unsigned short* __restrict__ Wkt,
    const unsigned short* __restrict__ Wvt, const float* __restrict__ bk,
    const float* __restrict__ bv, unsigned short* __restrict__ Kb,
    unsigned short* __restrict__ Vb) {
  __shared__ short WEb[128 * KST];  // 10240 B
  __shared__ short Wkb[128 * KST];  // 10240 B
  __shared__ short Wvb[128 * KST];  // 10240 B

  int bx = blockIdx.x;
  int v0 = (bx >> 1) * 128;
  int colbase = (bx & 1) * 128;
  int t = threadIdx.x;
  int w = t >> 6, lane = t & 63, a = lane & 15, quad = lane >> 4;
  int wm = w >> 1, wn = w & 1;

  // staging identity: thread covers (row sr, 16 k-cols starting at skc)
  int sr = t >> 1;
  int skc = (t & 1) * 16;

  f32x4 Ck[4][4], Cv[4][4];
#pragma unroll
  for (int mb = 0; mb < 4; ++mb)
#pragma unroll
    for (int nb = 0; nb < 4; ++nb) {
      Ck[mb][nb] = (f32x4){0.f, 0.f, 0.f, 0.f};
      Cv[mb][nb] = (f32x4){0.f, 0.f, 0.f, 0.f};
    }

  for (int kt = 0; kt < 24; ++kt) {
    // ---- issue global loads first (latency overlaps the barrier) ----
    int vrow = v0 + sr;
    float4 a0, a1, a2, a3;
    if (vrow < VV) {
      const float* wep = WE + (size_t)vrow * DW + kt * 32 + skc;
      a0 = *(const float4*)(wep + 0);
      a1 = *(const float4*)(wep + 4);
      a2 = *(const float4*)(wep + 8);
      a3 = *(const float4*)(wep + 12);
    } else {
      a0 = a1 = a2 = a3 = (float4){0.f, 0.f, 0.f, 0.f};
    }
    const unsigned short* kp = Wkt + (size_t)(colbase + sr) * DW + kt * 32 + skc;
    const unsigned short* vp = Wvt + (size_t)(colbase + sr) * DW + kt * 32 + skc;
    sh8 k0 = *(const sh8*)(kp + 0);
    sh8 k1 = *(const sh8*)(kp + 8);
    sh8 x0 = *(const sh8*)(vp + 0);
    sh8 x1 = *(const sh8*)(vp + 8);

    __syncthreads();  // previous iteration's frag reads done

    sh8 p0, p1;
    p0[0] = (short)bfbits(a0.x); p0[1] = (short)bfbits(a0.y);
    p0[2] = (short)bfbits(a0.z); p0[3] = (short)bfbits(a0.w);
    p0[4] = (short)bfbits(a1.x); p0[5] = (short)bfbits(a1.y);
    p0[6] = (short)bfbits(a1.z); p0[7] = (short)bfbits(a1.w);
    p1[0] = (short)bfbits(a2.x); p1[1] = (short)bfbits(a2.y);
    p1[2] = (short)bfbits(a2.z); p1[3] = (short)bfbits(a2.w);
    p1[4] = (short)bfbits(a3.x); p1[5] = (short)bfbits(a3.y);
    p1[6] = (short)bfbits(a3.z); p1[7] = (short)bfbits(a3.w);
    *(sh8*)&WEb[sr * KST + skc] = p0;
    *(sh8*)&WEb[sr * KST + skc + 8] = p1;
    *(sh8*)&Wkb[sr * KST + skc] = k0;
    *(sh8*)&Wkb[sr * KST + skc + 8] = k1;
    *(sh8*)&Wvb[sr * KST + skc] = x0;
    *(sh8*)&Wvb[sr * KST + skc + 8] = x1;
    __syncthreads();

    sh8 A[4], Bk[4], Bv[4];
#pragma unroll
    for (int mb = 0; mb < 4; ++mb)
      A[mb] = *(const sh8*)&WEb[(wm * 64 + mb * 16 + a) * KST + quad * 8];
#pragma unroll
    for (int nb = 0; nb < 4; ++nb) {
      Bk[nb] = *(const sh8*)&Wkb[((wn * 4 + nb) * 16 + a) * KST + quad * 8];
      Bv[nb] = *(const sh8*)&Wvb[((wn * 4 + nb) * 16 + a) * KST + quad * 8];
    }
#pragma unroll
    for (int mb = 0; mb < 4; ++mb)
#pragma unroll
      for (int nb = 0; nb < 4; ++nb) {
        Ck[mb][nb] = __builtin_amdgcn_mfma_f32_16x16x32_bf16(
            A[mb], Bk[nb], Ck[mb][nb], 0, 0, 0);
        Cv[mb][nb] = __builtin_amdgcn_mfma_f32_16x16x32_bf16(
            A[mb], Bv[nb], Cv[mb][nb], 0, 0, 0);
      }
  }

  // epilogue: bias + store bf16; pad rows -> 0
  float bkv[4], bvv[4];
#pragma unroll
  for (int nb = 0; nb < 4; ++nb) {
    int n = colbase + (wn * 4 + nb) * 16 + a;
    bkv[nb] = bk[n];
    bvv[nb] = bv[n];
  }
#pragma unroll
  for (int mb = 0; mb < 4; ++mb)
#pragma unroll
    for (int nb = 0; nb < 4; ++nb)
#pragma unroll
      for (int r = 0; r < 4; ++r) {
        int m = v0 + wm * 64 + mb * 16 + quad * 4 + r;
        int n = colbase + (wn * 4 + nb) * 16 + a;
        bool live = m < VV;
        Kb[(size_t)m * DM + n] = live ? bfbits(Ck[mb][nb][r] + bkv[nb]) : 0;
        Vb[(size_t)m * DM + n] = live ? bfbits(Cv[mb][nb][r] + bvv[nb]) : 0;
      }
}

// ---------------- zero the reprog accumulator -------------------------------
__global__ void zero_kernel(float* __restrict__ p, int n) {
  int i = blockIdx.x * blockDim.x + threadIdx.x;
  if (i < n) p[i] = 0.f;
}

// ---------------- MFMA attention over the vocab axis ------------------------
#define PST 72  // row stride (bf16) for Pb/Vt: 144 B = 16 B aligned
__global__ __launch_bounds__(256) void attn_kernel(
    const unsigned short* __restrict__ Qb, const unsigned short* __restrict__ Kb,
    const unsigned short* __restrict__ Vb, float* __restrict__ reprog, int bpb) {
  __shared__ short Pb[LL * PST];  // 18432 B
  __shared__ short Vt[EE * PST];  //  4608 B

  int bh = blockIdx.x / bpb;
  int chunk = blockIdx.x - bh * bpb;
  int b = bh >> 3, h = bh & 7;
  int t = threadIdx.x;
  int w = t >> 6;         // wave 0..3
  int lane = t & 63;
  int a = lane & 15;      // MFMA n / m lane coord
  int quad = lane >> 4;   // 0..3

  // hoist Q B-frags: frag[tau] holds Q rows l=tau*16+a, e=quad*8+j (16B each)
  sh8 qf[8];
  const unsigned short* qbase = Qb + (size_t)(b * LL) * DM + h * EE;
#pragma unroll
  for (int tau = 0; tau < 8; ++tau)
    qf[tau] = *(const sh8*)(qbase + (size_t)(tau * 16 + a) * DM + quad * 8);

  f32x4 C[2][2];  // accum: l = 32w + mb*16 + quad*4 + r, e = nb*16 + a
#pragma unroll
  for (int mb = 0; mb < 2; ++mb)
#pragma unroll
    for (int nb = 0; nb < 2; ++nb)
      C[mb][nb] = (f32x4){0.f, 0.f, 0.f, 0.f};

  const int ntiles = VPAD >> 6;  // 786
  for (int tile = chunk; tile < ntiles; tile += bpb) {
    int v0 = tile << 6;
    __syncthreads();  // prev phase2 done reading Pb/Vt

    // phase-1 A-frag: K row v = v0 + 16w + a, k=e = quad*8+j  (issue first)
    sh8 af = *(const sh8*)(Kb + (size_t)(v0 + 16 * w + a) * DM + h * EE + quad * 8);
    // V tile load for transposed staging (in flight during MFMA+softmax)
    int vr = t >> 2, e0 = (t & 3) * 8;
    sh8 vv = *(const sh8*)(Vb + (size_t)(v0 + vr) * DM + h * EE + e0);

    // scores: 8 MFMAs -> lane holds S for v rows {16w+quad*4+r}, l = tau*16+a
    f32x4 S[8];
#pragma unroll
    for (int tau = 0; tau < 8; ++tau) {
      f32x4 z = {0.f, 0.f, 0.f, 0.f};
      S[tau] = __builtin_amdgcn_mfma_f32_16x16x32_bf16(af, qf[tau], z, 0, 0, 0);
    }

    // register softmax over l (8 taus x 16 lanes of quad-group) per v-row r
    float mx[4], sm[4], inv[4];
#pragma unroll
    for (int r = 0; r < 4; ++r) {
      float m = S[0][r];
#pragma unroll
      for (int tau = 1; tau < 8; ++tau) m = fmaxf(m, S[tau][r]);
      mx[r] = m;
    }
#pragma unroll
    for (int msk = 1; msk <= 8; msk <<= 1)
#pragma unroll
      for (int r = 0; r < 4; ++r)
        mx[r] = fmaxf(mx[r], __shfl_xor(mx[r], msk));
#pragma unroll
    for (int r = 0; r < 4; ++r) sm[r] = 0.f;
#pragma unroll
    for (int tau = 0; tau < 8; ++tau)
#pragma unroll
      for (int r = 0; r < 4; ++r) {
        float ex = __expf(S[tau][r] - mx[r]);
        S[tau][r] = ex;
        sm[r] += ex;
      }
#pragma unroll
    for (int msk = 1; msk <= 8; msk <<= 1)
#pragma unroll
      for (int r = 0; r < 4; ++r)
        sm[r] += __shfl_xor(sm[r], msk);
#pragma unroll
    for (int r = 0; r < 4; ++r) inv[r] = 1.f / sm[r];

    // stage V^T: Vt[e][v_local]  (8 b16 scatter writes per thread)
    {
      const short* vs = (const short*)&vv;
#pragma unroll
      for (int j = 0; j < 8; ++j)
        Vt[(e0 + j) * PST + vr] = vs[j];
    }
    // write P^T bf16: Pb[l = tau*16+a][v_local = 16w + quad*4 + r]
#pragma unroll
    for (int tau = 0; tau < 8; ++tau) {
      ushort4 pk;
      pk.x = bfbits(S[tau][0] * inv[0]);
      pk.y = bfbits(S[tau][1] * inv[1]);
      pk.z = bfbits(S[tau][2] * inv[2]);
      pk.w = bfbits(S[tau][3] * inv[3]);
      *(ushort4*)&Pb[(tau * 16 + a) * PST + 16 * w + quad * 4] = pk;
    }
    __syncthreads();

    // phase 2: C[l][e] += P^T[l][v] · V[v][e]
    sh8 Afr[2][2], Bfr[2][2];
#pragma unroll
    for (int mb = 0; mb < 2; ++mb)
#pragma unroll
      for (int kb = 0; kb < 2; ++kb)
        Afr[mb][kb] =
            *(const sh8*)&Pb[(32 * w + mb * 16 + a) * PST + kb * 32 + quad * 8];
#pragma unroll
    for (int kb = 0; kb < 2; ++kb)
#pragma unroll
      for (int nb = 0; nb < 2; ++nb)
        Bfr[kb][nb] = *(const sh8*)&Vt[(nb * 16 + a) * PST + kb * 32 + quad * 8];
#pragma unroll
    for (int kb = 0; kb < 2; ++kb)
#pragma unroll
      for (int mb = 0; mb < 2; ++mb)
#pragma unroll
        for (int nb = 0; nb < 2; ++nb)
          C[mb][nb] = __builtin_amdgcn_mfma_f32_16x16x32_bf16(
              Afr[mb][kb], Bfr[kb][nb], C[mb][nb], 0, 0, 0);
  }

  // epilogue: one atomicAdd burst per block
#pragma unroll
  for (int mb = 0; mb < 2; ++mb)
#pragma unroll
    for (int nb = 0; nb < 2; ++nb)
#pragma unroll
      for (int r = 0; r < 4; ++r) {
        int l = 32 * w + mb * 16 + quad * 4 + r;
        int e = nb * 16 + a;
        atomicAdd(&reprog[(size_t)(b * LL + l) * DM + h * EE + e], C[mb][nb][r]);
      }
}

// ---------------- output projection: reprog @ Wo + bo -> fp32 out -----------
__global__ __launch_bounds__(256) void outproj_kernel(
    const float* __restrict__ reprog, const float* __restrict__ Wo,
    const float* __restrict__ bo, float* __restrict__ out) {
  __shared__ float row[DM];
  int r = blockIdx.x, n = threadIdx.x;
  row[n] = reprog[r * DM + n];
  __syncthreads();
  float acc = bo[n];
#pragma unroll 8
  for (int k = 0; k < DM; ++k)
    acc = fmaf(row[k], Wo[k * DM + n], acc);
  out[r * DM + n] = acc;
}

extern "C" void kernel_launch(void* const* d_in, const int* in_sizes, int n_in,
                              void* d_out, int out_size, void* d_ws, size_t ws_size,
                              hipStream_t stream) {
  const float* tse = (const float*)d_in[0];
  const float* WE  = (const float*)d_in[1];
  const float* Wq  = (const float*)d_in[2];
  const float* bq  = (const float*)d_in[3];
  const float* Wk  = (const float*)d_in[4];
  const float* bk  = (const float*)d_in[5];
  const float* Wv  = (const float*)d_in[6];
  const float* bv  = (const float*)d_in[7];
  const float* Wo  = (const float*)d_in[8];
  const float* bo  = (const float*)d_in[9];
  float* out = (float*)d_out;

  // ws: Qb | Kb | Vb | X, where X holds Wkt+Wvt during kvproj and is then
  // reused as reprog (lifetimes disjoint: wtrans->kvproj | zero->attn->outproj)
  char* ws = (char*)d_ws;
  const size_t QB_BYTES = (size_t)BB * LL * DM * 2;    // 262144
  const size_t KV_BYTES = (size_t)VPAD * DM * 2;       // 25755648
  const size_t WT_BYTES = (size_t)DM * DW * 2;         // 393216
  unsigned short* Qb  = (unsigned short*)ws;
  unsigned short* Kb  = (unsigned short*)(ws + QB_BYTES);
  unsigned short* Vb  = (unsigned short*)(ws + QB_BYTES + KV_BYTES);
  char* X = ws + QB_BYTES + 2 * KV_BYTES;
  unsigned short* Wkt = (unsigned short*)X;
  unsigned short* Wvt = (unsigned short*)(X + WT_BYTES);
  float* reprog = (float*)X;  // aliases Wkt/Wvt AFTER kvproj is done

  const int BPB = 32;  // v-chunks per (b,h): grid = 32*32 = 1024 blocks

  wtrans_kernel<<<2 * DM, 256, 0, stream>>>(Wk, Wv, Wkt, Wvt);
  qproj_kernel<<<BB * LL, 256, 0, stream>>>(tse, Wq, bq, Qb);
  kvproj_kernel<<<(VPAD / 128) * 2, 256, 0, stream>>>(WE, Wkt, Wvt, bk, bv, Kb, Vb);
  zero_kernel<<<(BB * LL * DM + 255) / 256, 256, 0, stream>>>(reprog, BB * LL * DM);
  attn_kernel<<<32 * BPB, 256, 0, stream>>>(Qb, Kb, Vb, reprog, BPB);
  outproj_kernel<<<BB * LL, 256, 0, stream>>>(reprog, Wo, bo, out);
}

// Round 5
// 419.744 us; speedup vs baseline: 4.6901x; 1.0490x over previous
//
#include <hip/hip_runtime.h>
#include <hip/hip_bf16.h>
#include <string.h>

#define BB 4
#define LL 128
#define DM 256
#define VV 50257
#define VPAD 50304   // 786 tiles * 64; also 393 * 128
#define DW 768
#define HH 8
#define EE 32

typedef __attribute__((ext_vector_type(8))) short sh8;    // 8 bf16 = 4 VGPR
typedef __attribute__((ext_vector_type(4))) short sh4;    // 4 bf16 = 2 VGPR
typedef __attribute__((ext_vector_type(4))) float f32x4;  // MFMA accum

static __device__ inline unsigned short bfbits(float x) {
  __hip_bfloat16 h = __float2bfloat16(x);
  unsigned short u;
  __builtin_memcpy(&u, &h, 2);
  return u;
}

static __device__ inline sh8 ld8_b64(const short* p) {  // two 8B LDS reads
  sh4 lo = *(const sh4*)p;
  sh4 hi = *(const sh4*)(p + 4);
  return __builtin_shufflevector(lo, hi, 0, 1, 2, 3, 4, 5, 6, 7);
}

// ---------------- Q projection: Qb = bf16(scale * (tse @ Wq + bq)) ----------
__global__ __launch_bounds__(256) void qproj_kernel(
    const float* __restrict__ tse, const float* __restrict__ Wq,
    const float* __restrict__ bq, unsigned short* __restrict__ Qb) {
  __shared__ float row[DM];
  int r = blockIdx.x;     // 0..511
  int n = threadIdx.x;    // 0..255
  row[n] = tse[r * DM + n];
  __syncthreads();
  float acc = bq[n];
#pragma unroll 8
  for (int k = 0; k < DM; ++k)
    acc = fmaf(row[k], Wq[k * DM + n], acc);
  const float scale = 0.17677669529663687f;  // 1/sqrt(32), folded into Q
  Qb[r * DM + n] = bfbits(acc * scale);
}

// ------- transpose+cast Wk/Wv fp32 [768][256] -> bf16 [256][768] ------------
// LDS 64x64 tile transpose: coalesced reads AND writes; [c][r] read is
// stride-65 -> conflict-free.
__global__ __launch_bounds__(256) void wtrans_kernel(
    const float* __restrict__ Wk, const float* __restrict__ Wv,
    unsigned short* __restrict__ Wkt, unsigned short* __restrict__ Wvt) {
  __shared__ float tileS[64][65];
  const float* src = blockIdx.z ? Wv : Wk;
  unsigned short* dst = blockIdx.z ? Wvt : Wkt;
  int k0 = blockIdx.x * 64, n0 = blockIdx.y * 64;
  int t = threadIdx.x;
  int c = t & 63, rb = t >> 6;
#pragma unroll
  for (int j = 0; j < 16; ++j) {
    int r = j * 4 + rb;
    tileS[r][c] = src[(size_t)(k0 + r) * DM + n0 + c];
  }
  __syncthreads();
#pragma unroll
  for (int j = 0; j < 16; ++j) {
    int r = j * 4 + rb;
    dst[(size_t)(n0 + r) * DW + k0 + c] = bfbits(tileS[c][r]);
  }
}

// ------------- K,V projection via MFMA: [VPAD,768]@[768,256] x2 -------------
// Block: 128 rows x 128 cols of both K and V (sharing WE A-tiles).
// Software-pipelined: global loads for kt+1 issued before the MFMAs of kt.
// LDS stride 36 bf16 (72 B, dword-stride 18, gcd(18,32)=2) + b64 accesses.
#define KST2 36
__global__ __launch_bounds__(256, 2) void kvproj_kernel(
    const float* __restrict__ WE, const unsigned short* __restrict__ Wkt,
    const unsigned short* __restrict__ Wvt, const float* __restrict__ bk,
    const float* __restrict__ bv, unsigned short* __restrict__ Kb,
    unsigned short* __restrict__ Vb) {
  __shared__ short WEb[128 * KST2];  // 9216 B
  __shared__ short Wkb[128 * KST2];  // 9216 B
  __shared__ short Wvb[128 * KST2];  // 9216 B

  int bx = blockIdx.x;
  int v0 = (bx >> 1) * 128;
  int colbase = (bx & 1) * 128;
  int t = threadIdx.x;
  int w = t >> 6, lane = t & 63, a = lane & 15, quad = lane >> 4;
  int wm = w >> 1, wn = w & 1;
  // staging identity: row sr, 16-bf16 half skc
  int sr = t >> 1;
  int skc = (t & 1) * 16;
  const bool live = (v0 + sr) < VV;  // block-uniform except last block

  float4 a0, a1, a2, a3;
  sh8 k0, k1, x0, x1;

  auto issue_loads = [&](int kt) {
    if (live) {
      const float* wep = WE + (size_t)(v0 + sr) * DW + kt * 32 + skc;
      a0 = *(const float4*)(wep + 0);
      a1 = *(const float4*)(wep + 4);
      a2 = *(const float4*)(wep + 8);
      a3 = *(const float4*)(wep + 12);
    } else {
      a0 = a1 = a2 = a3 = (float4){0.f, 0.f, 0.f, 0.f};
    }
    const unsigned short* kp = Wkt + (size_t)(colbase + sr) * DW + kt * 32 + skc;
    const unsigned short* vp = Wvt + (size_t)(colbase + sr) * DW + kt * 32 + skc;
    k0 = *(const sh8*)(kp + 0);
    k1 = *(const sh8*)(kp + 8);
    x0 = *(const sh8*)(vp + 0);
    x1 = *(const sh8*)(vp + 8);
  };

  f32x4 Ck[4][4], Cv[4][4];
#pragma unroll
  for (int mb = 0; mb < 4; ++mb)
#pragma unroll
    for (int nb = 0; nb < 4; ++nb) {
      Ck[mb][nb] = (f32x4){0.f, 0.f, 0.f, 0.f};
      Cv[mb][nb] = (f32x4){0.f, 0.f, 0.f, 0.f};
    }

  issue_loads(0);

  for (int kt = 0; kt < 24; ++kt) {
    __syncthreads();  // previous iteration's frag reads done

    // convert + store this kt's tiles (b64, conflict-light layout)
    {
      sh4 w0 = {(short)bfbits(a0.x), (short)bfbits(a0.y),
                (short)bfbits(a0.z), (short)bfbits(a0.w)};
      sh4 w1 = {(short)bfbits(a1.x), (short)bfbits(a1.y),
                (short)bfbits(a1.z), (short)bfbits(a1.w)};
      sh4 w2 = {(short)bfbits(a2.x), (short)bfbits(a2.y),
                (short)bfbits(a2.z), (short)bfbits(a2.w)};
      sh4 w3 = {(short)bfbits(a3.x), (short)bfbits(a3.y),
                (short)bfbits(a3.z), (short)bfbits(a3.w)};
      short* eb = &WEb[sr * KST2 + skc];
      *(sh4*)(eb + 0) = w0;
      *(sh4*)(eb + 4) = w1;
      *(sh4*)(eb + 8) = w2;
      *(sh4*)(eb + 12) = w3;
      short* kb = &Wkb[sr * KST2 + skc];
      *(sh4*)(kb + 0) = __builtin_shufflevector(k0, k0, 0, 1, 2, 3);
      *(sh4*)(kb + 4) = __builtin_shufflevector(k0, k0, 4, 5, 6, 7);
      *(sh4*)(kb + 8) = __builtin_shufflevector(k1, k1, 0, 1, 2, 3);
      *(sh4*)(kb + 12) = __builtin_shufflevector(k1, k1, 4, 5, 6, 7);
      short* vb = &Wvb[sr * KST2 + skc];
      *(sh4*)(vb + 0) = __builtin_shufflevector(x0, x0, 0, 1, 2, 3);
      *(sh4*)(vb + 4) = __builtin_shufflevector(x0, x0, 4, 5, 6, 7);
      *(sh4*)(vb + 8) = __builtin_shufflevector(x1, x1, 0, 1, 2, 3);
      *(sh4*)(vb + 12) = __builtin_shufflevector(x1, x1, 4, 5, 6, 7);
    }
    __syncthreads();

    // prefetch kt+1 (in flight during frag reads + MFMAs + next barrier)
    if (kt < 23) issue_loads(kt + 1);

    sh8 A[4], Bk[4], Bv[4];
#pragma unroll
    for (int mb = 0; mb < 4; ++mb)
      A[mb] = ld8_b64(&WEb[(wm * 64 + mb * 16 + a) * KST2 + quad * 8]);
#pragma unroll
    for (int nb = 0; nb < 4; ++nb) {
      Bk[nb] = ld8_b64(&Wkb[((wn * 4 + nb) * 16 + a) * KST2 + quad * 8]);
      Bv[nb] = ld8_b64(&Wvb[((wn * 4 + nb) * 16 + a) * KST2 + quad * 8]);
    }
#pragma unroll
    for (int mb = 0; mb < 4; ++mb)
#pragma unroll
      for (int nb = 0; nb < 4; ++nb) {
        Ck[mb][nb] = __builtin_amdgcn_mfma_f32_16x16x32_bf16(
            A[mb], Bk[nb], Ck[mb][nb], 0, 0, 0);
        Cv[mb][nb] = __builtin_amdgcn_mfma_f32_16x16x32_bf16(
            A[mb], Bv[nb], Cv[mb][nb], 0, 0, 0);
      }
  }

  // epilogue: bias + store bf16; pad rows -> 0
  float bkv[4], bvv[4];
#pragma unroll
  for (int nb = 0; nb < 4; ++nb) {
    int n = colbase + (wn * 4 + nb) * 16 + a;
    bkv[nb] = bk[n];
    bvv[nb] = bv[n];
  }
#pragma unroll
  for (int mb = 0; mb < 4; ++mb)
#pragma unroll
    for (int nb = 0; nb < 4; ++nb)
#pragma unroll
      for (int r = 0; r < 4; ++r) {
        int m = v0 + wm * 64 + mb * 16 + quad * 4 + r;
        int n = colbase + (wn * 4 + nb) * 16 + a;
        bool ok = m < VV;
        Kb[(size_t)m * DM + n] = ok ? bfbits(Ck[mb][nb][r] + bkv[nb]) : 0;
        Vb[(size_t)m * DM + n] = ok ? bfbits(Cv[mb][nb][r] + bvv[nb]) : 0;
      }
}

// ---------------- zero the reprog accumulator -------------------------------
__global__ void zero_kernel(float* __restrict__ p, int n) {
  int i = blockIdx.x * blockDim.x + threadIdx.x;
  if (i < n) p[i] = 0.f;
}

// ---------------- MFMA attention over the vocab axis ------------------------
// Software-pipelined: K-frag / V-rows for tile+1 loaded during phase 2.
#define PST 72  // row stride (bf16) for Pb/Vt: 144 B = 16 B aligned
__global__ __launch_bounds__(256) void attn_kernel(
    const unsigned short* __restrict__ Qb, const unsigned short* __restrict__ Kb,
    const unsigned short* __restrict__ Vb, float* __restrict__ reprog, int bpb) {
  __shared__ short Pb[LL * PST];  // 18432 B
  __shared__ short Vt[EE * PST];  //  4608 B

  int bh = blockIdx.x / bpb;
  int chunk = blockIdx.x - bh * bpb;
  int b = bh >> 3, h = bh & 7;
  int t = threadIdx.x;
  int w = t >> 6;         // wave 0..3
  int lane = t & 63;
  int a = lane & 15;      // MFMA n / m lane coord
  int quad = lane >> 4;   // 0..3
  int vr = t >> 2, e0 = (t & 3) * 8;  // V staging identity

  // hoist Q B-frags: frag[tau] holds Q rows l=tau*16+a, e=quad*8+j (16B each)
  sh8 qf[8];
  const unsigned short* qbase = Qb + (size_t)(b * LL) * DM + h * EE;
#pragma unroll
  for (int tau = 0; tau < 8; ++tau)
    qf[tau] = *(const sh8*)(qbase + (size_t)(tau * 16 + a) * DM + quad * 8);

  f32x4 C[2][2];  // accum: l = 32w + mb*16 + quad*4 + r, e = nb*16 + a
#pragma unroll
  for (int mb = 0; mb < 2; ++mb)
#pragma unroll
    for (int nb = 0; nb < 2; ++nb)
      C[mb][nb] = (f32x4){0.f, 0.f, 0.f, 0.f};

  const int ntiles = VPAD >> 6;  // 786

  // prefetch first tile
  sh8 af, vv;
  {
    int v0 = chunk << 6;
    af = *(const sh8*)(Kb + (size_t)(v0 + 16 * w + a) * DM + h * EE + quad * 8);
    vv = *(const sh8*)(Vb + (size_t)(v0 + vr) * DM + h * EE + e0);
  }

  for (int tile = chunk; tile < ntiles; tile += bpb) {
    // scores: 8 MFMAs on prefetched af
    f32x4 S[8];
#pragma unroll
    for (int tau = 0; tau < 8; ++tau) {
      f32x4 z = {0.f, 0.f, 0.f, 0.f};
      S[tau] = __builtin_amdgcn_mfma_f32_16x16x32_bf16(af, qf[tau], z, 0, 0, 0);
    }

    // register softmax over l per v-row r (shfl within 16-lane quad groups)
    float mx[4], sm[4], inv[4];
#pragma unroll
    for (int r = 0; r < 4; ++r) {
      float m = S[0][r];
#pragma unroll
      for (int tau = 1; tau < 8; ++tau) m = fmaxf(m, S[tau][r]);
      mx[r] = m;
    }
#pragma unroll
    for (int msk = 1; msk <= 8; msk <<= 1)
#pragma unroll
      for (int r = 0; r < 4; ++r)
        mx[r] = fmaxf(mx[r], __shfl_xor(mx[r], msk));
#pragma unroll
    for (int r = 0; r < 4; ++r) sm[r] = 0.f;
#pragma unroll
    for (int tau = 0; tau < 8; ++tau)
#pragma unroll
      for (int r = 0; r < 4; ++r) {
        float ex = __expf(S[tau][r] - mx[r]);
        S[tau][r] = ex;
        sm[r] += ex;
      }
#pragma unroll
    for (int msk = 1; msk <= 8; msk <<= 1)
#pragma unroll
      for (int r = 0; r < 4; ++r)
        sm[r] += __shfl_xor(sm[r], msk);
#pragma unroll
    for (int r = 0; r < 4; ++r) inv[r] = 1.f / sm[r];

    __syncthreads();  // prev phase2 frag reads done

    // stage V^T: Vt[e][v_local]
    {
      const short* vs = (const short*)&vv;
#pragma unroll
      for (int j = 0; j < 8; ++j)
        Vt[(e0 + j) * PST + vr] = vs[j];
    }
    // write P^T bf16: Pb[l = tau*16+a][v_local = 16w + quad*4 + r]
#pragma unroll
    for (int tau = 0; tau < 8; ++tau) {
      ushort4 pk;
      pk.x = bfbits(S[tau][0] * inv[0]);
      pk.y = bfbits(S[tau][1] * inv[1]);
      pk.z = bfbits(S[tau][2] * inv[2]);
      pk.w = bfbits(S[tau][3] * inv[3]);
      *(ushort4*)&Pb[(tau * 16 + a) * PST + 16 * w + quad * 4] = pk;
    }
    __syncthreads();

    // prefetch next tile's K-frag + V-rows (hidden behind phase 2)
    int nt = tile + bpb;
    if (nt < ntiles) {
      int v0n = nt << 6;
      af = *(const sh8*)(Kb + (size_t)(v0n + 16 * w + a) * DM + h * EE + quad * 8);
      vv = *(const sh8*)(Vb + (size_t)(v0n + vr) * DM + h * EE + e0);
    }

    // phase 2: C[l][e] += P^T[l][v] · V[v][e]
    sh8 Afr[2][2], Bfr[2][2];
#pragma unroll
    for (int mb = 0; mb < 2; ++mb)
#pragma unroll
      for (int kb = 0; kb < 2; ++kb)
        Afr[mb][kb] =
            *(const sh8*)&Pb[(32 * w + mb * 16 + a) * PST + kb * 32 + quad * 8];
#pragma unroll
    for (int kb = 0; kb < 2; ++kb)
#pragma unroll
      for (int nb = 0; nb < 2; ++nb)
        Bfr[kb][nb] = *(const sh8*)&Vt[(nb * 16 + a) * PST + kb * 32 + quad * 8];
#pragma unroll
    for (int kb = 0; kb < 2; ++kb)
#pragma unroll
      for (int mb = 0; mb < 2; ++mb)
#pragma unroll
        for (int nb = 0; nb < 2; ++nb)
          C[mb][nb] = __builtin_amdgcn_mfma_f32_16x16x32_bf16(
              Afr[mb][kb], Bfr[kb][nb], C[mb][nb], 0, 0, 0);
  }

  // epilogue: one atomicAdd burst per block
#pragma unroll
  for (int mb = 0; mb < 2; ++mb)
#pragma unroll
    for (int nb = 0; nb < 2; ++nb)
#pragma unroll
      for (int r = 0; r < 4; ++r) {
        int l = 32 * w + mb * 16 + quad * 4 + r;
        int e = nb * 16 + a;
        atomicAdd(&reprog[(size_t)(b * LL + l) * DM + h * EE + e], C[mb][nb][r]);
      }
}

// ---------------- output projection: reprog @ Wo + bo -> fp32 out -----------
__global__ __launch_bounds__(256) void outproj_kernel(
    const float* __restrict__ reprog, const float* __restrict__ Wo,
    const float* __restrict__ bo, float* __restrict__ out) {
  __shared__ float row[DM];
  int r = blockIdx.x, n = threadIdx.x;
  row[n] = reprog[r * DM + n];
  __syncthreads();
  float acc = bo[n];
#pragma unroll 8
  for (int k = 0; k < DM; ++k)
    acc = fmaf(row[k], Wo[k * DM + n], acc);
  out[r * DM + n] = acc;
}

extern "C" void kernel_launch(void* const* d_in, const int* in_sizes, int n_in,
                              void* d_out, int out_size, void* d_ws, size_t ws_size,
                              hipStream_t stream) {
  const float* tse = (const float*)d_in[0];
  const float* WE  = (const float*)d_in[1];
  const float* Wq  = (const float*)d_in[2];
  const float* bq  = (const float*)d_in[3];
  const float* Wk  = (const float*)d_in[4];
  const float* bk  = (const float*)d_in[5];
  const float* Wv  = (const float*)d_in[6];
  const float* bv  = (const float*)d_in[7];
  const float* Wo  = (const float*)d_in[8];
  const float* bo  = (const float*)d_in[9];
  float* out = (float*)d_out;

  // ws: Qb | Kb | Vb | X, where X holds Wkt+Wvt during kvproj and is then
  // reused as reprog (lifetimes disjoint: wtrans->kvproj | zero->attn->outproj)
  char* ws = (char*)d_ws;
  const size_t QB_BYTES = (size_t)BB * LL * DM * 2;    // 262144
  const size_t KV_BYTES = (size_t)VPAD * DM * 2;       // 25755648
  const size_t WT_BYTES = (size_t)DM * DW * 2;         // 393216
  unsigned short* Qb  = (unsigned short*)ws;
  unsigned short* Kb  = (unsigned short*)(ws + QB_BYTES);
  unsigned short* Vb  = (unsigned short*)(ws + QB_BYTES + KV_BYTES);
  char* X = ws + QB_BYTES + 2 * KV_BYTES;
  unsigned short* Wkt = (unsigned short*)X;
  unsigned short* Wvt = (unsigned short*)(X + WT_BYTES);
  float* reprog = (float*)X;  // aliases Wkt/Wvt AFTER kvproj is done

  const int BPB = 32;  // v-chunks per (b,h): grid = 32*32 = 1024 blocks

  wtrans_kernel<<<dim3(DW / 64, DM / 64, 2), 256, 0, stream>>>(Wk, Wv, Wkt, Wvt);
  qproj_kernel<<<BB * LL, 256, 0, stream>>>(tse, Wq, bq, Qb);
  kvproj_kernel<<<(VPAD / 128) * 2, 256, 0, stream>>>(WE, Wkt, Wvt, bk, bv, Kb, Vb);
  zero_kernel<<<(BB * LL * DM + 255) / 256, 256, 0, stream>>>(reprog, BB * LL * DM);
  attn_kernel<<<32 * BPB, 256, 0, stream>>>(Qb, Kb, Vb, reprog, BPB);
  outproj_kernel<<<BB * LL, 256, 0, stream>>>(reprog, Wo, bo, out);
}